// Round 5
// baseline (13993.904 us; speedup 1.0000x reference)
//
#include <hip/hip_runtime.h>
#include <hip/hip_fp16.h>
#include <cstdint>
#include <cstddef>

#define B_ 256
#define L_ 200
#define S_ 199
#define D_ 256
#define Q_ 20000
#define C_ 500
#define NB 256

// ---- workspace layout (bytes, 256-aligned) ----
#define OFF_TEPF 0u            // 204800  f32 [200][256]
#define OFF_TESF 204800u       // 204800
#define OFF_CAF  409600u       // 1024
#define OFF_EXLA 410624u       // 131072  f16 [B][256]
#define OFF_EXLP 541696u       // 131072
#define OFF_EXLC 672768u       // 131072
#define OFF_EXAS 803840u       // 262144  f32 [B][256]
#define OFF_OACC 1065984u      // 203776  f32 [B][S]
#define OFF_BAR  1269760u      // 256
#define OFF_LPI  1270016u      // 203776  int [B][S]
#define OFF_LCI  1473792u      // 203776
#define OFF_PS   1677568u      // 52166656 f32 [B][S][256]
#define OFF_SS   53844224u     // 52166656
// total 106,010,880 bytes (~101.1 MB; round-2 proved >=106.4 MB available)

// TEpf[tau][d] = bpf[d] + sum_k time_embed[tau][k]*Wpf[d][256+k]; same for sf.
__global__ void te_kernel(const float* __restrict__ te,
                          const float* __restrict__ Wpf, const float* __restrict__ bpf,
                          const float* __restrict__ Wsf, const float* __restrict__ bsf,
                          float* __restrict__ TEpf, float* __restrict__ TEsf) {
  int idx = blockIdx.x * 256 + threadIdx.x;
  int tau = idx >> 8, d = idx & 255;
  const float* ter = te + (tau << 8);
  const float* wp = Wpf + d * 512 + 256;
  const float* ws = Wsf + d * 512 + 256;
  float ap = 0.f, as = 0.f;
  for (int k = 0; k < 256; ++k) {
    float x = ter[k];
    ap = fmaf(x, wp[k], ap);
    as = fmaf(x, ws[k], as);
  }
  TEpf[idx] = ap + bpf[d];
  TEsf[idx] = as + bsf[d];
}

__global__ void caf_kernel(const float* __restrict__ te, const float* __restrict__ Waf,
                           const float* __restrict__ baf, float* __restrict__ CAF) {
  int d = threadIdx.x;
  const float* ter = te + 256;
  const float* wa = Waf + d * 512 + 256;
  float a = 0.f;
  for (int k = 0; k < 256; ++k) a = fmaf(ter[k], wa[k], a);
  CAF[d] = a + baf[d];
}

// lpi[b][t] = largest t'<t with nq[b][t']==nq[b][t], else 0 (matches lpt-table
// semantics incl. "never seen" -> 0, since step 0 overwrites history row 0).
__global__ void lastidx_kernel(const int* __restrict__ q_seq, const int* __restrict__ c_seq,
                               int* __restrict__ lpi, int* __restrict__ lci) {
  int b = blockIdx.x;
  int tid = threadIdx.x;
  __shared__ int sq[S_], sc[S_];
  if (tid < S_) {
    sq[tid] = q_seq[b * L_ + tid + 1];
    sc[tid] = c_seq[b * L_ + tid + 1];
  }
  __syncthreads();
  if (tid < S_) {
    int ip = sq[tid], ic = sc[tid];
    int lp = 0, lc = 0;
    for (int u = tid - 1; u >= 0; --u) if (sq[u] == ip) { lp = u; break; }
    for (int u = tid - 1; u >= 0; --u) if (sc[u] == ic) { lc = u; break; }
    lpi[b * S_ + tid] = lp;
    lci[b * S_ + tid] = lc;
  }
}

typedef _Float16 h2v __attribute__((ext_vector_type(2)));
union U2H { unsigned u; h2v h; __half2 hh; };

__device__ __forceinline__ float fd2(unsigned w, unsigned x, float acc) {
#if __has_builtin(__builtin_amdgcn_fdot2)
  U2H a; a.u = w; U2H b; b.u = x;
  return __builtin_amdgcn_fdot2(a.h, b.h, acc, false);
#else
  U2H a; a.u = w; U2H b; b.u = x;
  acc = fmaf(__low2float(a.hh),  __low2float(b.hh),  acc);
  acc = fmaf(__high2float(a.hh), __high2float(b.hh), acc);
  return acc;
#endif
}
__device__ __forceinline__ float dot8(uint4 w, uint4 x, float acc) {
  acc = fd2(w.x, x.x, acc); acc = fd2(w.y, x.y, acc);
  acc = fd2(w.z, x.z, acc); acc = fd2(w.w, x.w, acc);
  return acc;
}
__device__ __forceinline__ float sigf(float z) { return 1.f / (1.f + __expf(-z)); }
__device__ __forceinline__ float tanh_fast(float z) { return 1.f - 2.f / (__expf(2.f * z) + 1.f); }
__device__ __forceinline__ void st4h(__half* dst, float4 v) {
  dst[0] = __float2half(v.x); dst[1] = __float2half(v.y);
  dst[2] = __float2half(v.z); dst[3] = __float2half(v.w);
}

struct KParams {
  const int *qs, *cs, *aseq;
  const float *pro, *skill, *ansv, *lsst, *ps0, *ss0, *adiff, *achg;
  const float *Wpf, *Wsf, *Waf, *Was, *Wps, *Wss, *Wo1;
  const float *bo1, *bas, *bps, *bss, *Wo2;
  const float *TEpf, *TEsf, *CAF;
  const int *lpi, *lci;
  __half *EXla, *EXlp, *EXlc;
  float *EXas, *psh, *ssh, *outacc;
  unsigned *bar;
};

// sense-reversing grid barrier; bar[0]=count, bar[32]=epoch (separate lines)
__device__ __forceinline__ void grid_barrier(unsigned* bar) {
  __syncthreads();
  if (threadIdx.x == 0) {
    __threadfence();
    unsigned* cnt = bar;
    unsigned* epo = bar + 32;
    unsigned e = __hip_atomic_load(epo, __ATOMIC_RELAXED, __HIP_MEMORY_SCOPE_AGENT);
    unsigned a = __hip_atomic_fetch_add(cnt, 1u, __ATOMIC_ACQ_REL, __HIP_MEMORY_SCOPE_AGENT);
    if (a == NB - 1u) {
      __hip_atomic_store(cnt, 0u, __ATOMIC_RELAXED, __HIP_MEMORY_SCOPE_AGENT);
      __hip_atomic_store(epo, e + 1u, __ATOMIC_RELEASE, __HIP_MEMORY_SCOPE_AGENT);
    } else {
      while (__hip_atomic_load(epo, __ATOMIC_ACQUIRE, __HIP_MEMORY_SCOPE_AGENT) == e) {
        __builtin_amdgcn_s_sleep(1);
      }
    }
    __threadfence();
  }
  __syncthreads();
}

// 256 blocks = (group g: 16 rows) x (slice s: 16 output dims). 256 threads = (r, c).
__global__ __launch_bounds__(256)
void scan_coop(KParams p) {
  const int bid = blockIdx.x;
  const int g = bid >> 4, s = bid & 15;
  const int tid = threadIdx.x;
  const int r = tid >> 4;          // local row 0..15
  const int c = tid & 15;          // local out-dim 0..15
  const int row = (g << 4) + r;
  const int dset = (s << 4) + c;   // this thread's output dim

  __shared__ __align__(16) __half wgp[3][16][264];   // gate left halves   25344 B
  __shared__ __align__(16) __half wup[3][16][520];   // update (as,ps,ss)  49920 B
  __shared__ __align__(16) __half wo1l[16][1032];    // Wo1 slice          33024 B
  __shared__ __align__(16) __half act[5][16][264];   // 0..2 varying, 3=pe, 4=x
  __shared__ int s_ip[16], s_ic[16], s_ia[16], s_lp[16], s_lc[16];

  // ---- load weight slices to LDS ----
  {
    const int wrow = (s << 4) + r;
    for (int m = 0; m < 3; ++m) {
      const float* W = (m == 0 ? p.Wpf : m == 1 ? p.Wsf : p.Waf) + wrow * 512;
      for (int j = 0; j < 4; ++j) {
        float4 v = *(const float4*)(W + c * 16 + j * 4);
        st4h(&wgp[m][r][c * 16 + j * 4], v);
      }
    }
    for (int m = 0; m < 3; ++m) {
      const float* W = (m == 0 ? p.Was : m == 1 ? p.Wps : p.Wss) + wrow * 512;
      for (int j = 0; j < 8; ++j) {
        float4 v = *(const float4*)(W + c * 32 + j * 4);
        st4h(&wup[m][r][c * 32 + j * 4], v);
      }
    }
    const float* W = p.Wo1 + wrow * 1024;
    for (int j = 0; j < 16; ++j) {
      float4 v = *(const float4*)(W + c * 64 + j * 4);
      st4h(&wo1l[r][c * 64 + j * 4], v);
    }
  }
  const float caf_r = p.CAF[dset];
  const float bo1_r = p.bo1[dset];
  const float bas_r = p.bas[dset];
  const float bps_r = p.bps[dset];
  const float bss_r = p.bss[dset];
  const float wo2_r = p.Wo2[dset];

  // ---- state init (s==0 blocks own their 16 rows) ----
  if (s == 0) {
    for (int j = 0; j < 16; ++j) {
      int k = c * 16 + j;
      p.EXas[row * 256 + k] = p.lsst[k];
      p.psh[(size_t)row * S_ * 256 + k] = p.ps0[k];   // lazy row-0 init
      p.ssh[(size_t)row * S_ * 256 + k] = p.ss0[k];
    }
  }
  grid_barrier(p.bar);

#pragma clang loop unroll(disable)
  for (int t = 0; t < S_; ++t) {
    if (tid < 16) {
      int rowr = (g << 4) + tid;
      s_ip[tid] = p.qs[rowr * L_ + t + 1];
      s_ic[tid] = p.cs[rowr * L_ + t + 1];
      s_ia[tid] = p.aseq[rowr * L_ + t + 1];
      s_lp[tid] = p.lpi[rowr * S_ + t];
      s_lc[tid] = p.lci[rowr * S_ + t];
    }
    __syncthreads();

    // --- gathers: lp, lc, ast (f32 -> f16 LDS) + pe/x from embeds ---
    {
      const int lpt_r = s_lp[r], lct_r = s_lc[r];
      const float4* srcp = (const float4*)(p.psh + ((size_t)row * S_ + lpt_r) * 256);
      const float4* srcs = (const float4*)(p.ssh + ((size_t)row * S_ + lct_r) * 256);
      const float4* srca = (const float4*)(p.EXas + (size_t)row * 256);
      for (int j = 0; j < 4; ++j) {
        int k4 = (c << 2) + j;     // 0..63
        st4h(&act[0][r][k4 * 4], srcp[k4]);
        st4h(&act[1][r][k4 * 4], srcs[k4]);
        st4h(&act[2][r][k4 * 4], srca[k4]);
      }
      int ip = s_ip[r], ic = s_ic[r], ia = s_ia[r];
      float ad = p.adiff[ip];
      const float4* pp = (const float4*)(p.pro   + (size_t)ip * 256);
      const float4* sp = (const float4*)(p.skill + (size_t)ic * 256);
      const float4* cp = (const float4*)(p.achg  + (size_t)ic * 256);
      const float4* ap = (const float4*)(p.ansv  + (size_t)ia * 256);
      for (int j = 0; j < 4; ++j) {
        int k4 = c + (j << 4);
        float4 a = pp[k4], b = sp[k4], dd = cp[k4], e = ap[k4];
        float4 pe4 = make_float4(a.x + b.x + ad * dd.x, a.y + b.y + ad * dd.y,
                                 a.z + b.z + ad * dd.z, a.w + b.w + ad * dd.w);
        float4 x4 = make_float4(pe4.x + e.x, pe4.y + e.y, pe4.z + e.z, pe4.w + e.w);
        st4h(&act[3][r][k4 * 4], pe4);
        st4h(&act[4][r][k4 * 4], x4);
      }
    }
    __syncthreads();

    // --- f32 carry scalars for (row, dset) ---
    const int lpt_r = s_lp[r], lct_r = s_lc[r];
    const float lp_v = p.psh[((size_t)row * S_ + lpt_r) * 256 + dset];
    const float lc_v = p.ssh[((size_t)row * S_ + lct_r) * 256 + dset];
    const float as_v = p.EXas[(size_t)row * 256 + dset];
    const float dtp = p.TEpf[(t - lpt_r) * 256 + dset];
    const float dtc = p.TEsf[(t - lct_r) * 256 + dset];

    // --- phase 1: gate dots (K=256 each) ---
    float a0 = 0.f, a1 = 0.f, a2 = 0.f;
    {
      const uint4* w0 = (const uint4*)&wgp[0][c][0];
      const uint4* w1 = (const uint4*)&wgp[1][c][0];
      const uint4* w2 = (const uint4*)&wgp[2][c][0];
      const uint4* x0 = (const uint4*)&act[0][r][0];
      const uint4* x1 = (const uint4*)&act[1][r][0];
      const uint4* x2 = (const uint4*)&act[2][r][0];
#pragma unroll 8
      for (int k = 0; k < 32; ++k) {
        a0 = dot8(w0[k], x0[k], a0);
        a1 = dot8(w1[k], x1[k], a1);
        a2 = dot8(w2[k], x2[k], a2);
      }
    }
    const float lp2 = lp_v * sigf(a0 + dtp);
    const float lc2 = lc_v * sigf(a1 + dtc);
    const float la2 = as_v * sigf(a2 + caf_r);
    p.EXlp[row * 256 + dset] = __float2half(lp2);
    p.EXlc[row * 256 + dset] = __float2half(lc2);
    p.EXla[row * 256 + dset] = __float2half(la2);

    grid_barrier(p.bar);   // A: slice outputs exchanged

    // --- phase 2 staging: full la/lp2/lc2 vectors (f16) ---
    {
      const uint4* sla = (const uint4*)(p.EXla + (size_t)row * 256);
      const uint4* slp = (const uint4*)(p.EXlp + (size_t)row * 256);
      const uint4* slc = (const uint4*)(p.EXlc + (size_t)row * 256);
      uint4* d0 = (uint4*)&act[0][r][0];
      uint4* d1 = (uint4*)&act[1][r][0];
      uint4* d2 = (uint4*)&act[2][r][0];
      d0[c] = sla[c]; d0[c + 16] = sla[c + 16];
      d1[c] = slp[c]; d1[c + 16] = slp[c + 16];
      d2[c] = slc[c]; d2[c + 16] = slc[c + 16];
    }
    __syncthreads();

    // --- phase 2: Wo1 (K=1024, segs [la|lp2|lc2|pe]) + updates (K=512, [state|x]) ---
    float accO = 0.f, accA = 0.f, accP = 0.f, accC = 0.f;
    {
      const uint4* wO = (const uint4*)&wo1l[c][0];    // 128 uint4
      const uint4* wA = (const uint4*)&wup[0][c][0];  // 64 uint4
      const uint4* wP = (const uint4*)&wup[1][c][0];
      const uint4* wC = (const uint4*)&wup[2][c][0];
      const uint4* xla = (const uint4*)&act[0][r][0]; // 32 uint4 each
      const uint4* xlp = (const uint4*)&act[1][r][0];
      const uint4* xlc = (const uint4*)&act[2][r][0];
      const uint4* xpe = (const uint4*)&act[3][r][0];
      const uint4* xx  = (const uint4*)&act[4][r][0];
#pragma unroll 8
      for (int k = 0; k < 32; ++k) {
        uint4 vla = xla[k];
        accO = dot8(wO[k], vla, accO);
        accA = dot8(wA[k], vla, accA);
        accP = dot8(wP[k], xlp[k], accP);
        accC = dot8(wC[k], xlc[k], accC);
      }
#pragma unroll 8
      for (int k = 0; k < 32; ++k) {
        uint4 vx = xx[k];
        accO = dot8(wO[32 + k], xlp[k], accO);
        accA = dot8(wA[32 + k], vx, accA);
        accP = dot8(wP[32 + k], vx, accP);
        accC = dot8(wC[32 + k], vx, accC);
      }
#pragma unroll 8
      for (int k = 0; k < 32; ++k) {
        accO = dot8(wO[64 + k], xlc[k], accO);
        accO = dot8(wO[96 + k], xpe[k], accO);
      }
    }
    float o1 = fmaxf(accO + bo1_r, 0.f) * wo2_r;
    o1 += __shfl_xor(o1, 1); o1 += __shfl_xor(o1, 2);
    o1 += __shfl_xor(o1, 4); o1 += __shfl_xor(o1, 8);
    if (c == 0) atomicAdd(&p.outacc[row * S_ + t], o1);

    const float anew = la2 + tanh_fast(accA + bas_r);
    const float pnew = lp2 + tanh_fast(accP + bps_r);
    const float cnew = lc2 + tanh_fast(accC + bss_r);
    p.EXas[(size_t)row * 256 + dset] = anew;
    p.psh[((size_t)row * S_ + t) * 256 + dset] = pnew;
    p.ssh[((size_t)row * S_ + t) * 256 + dset] = cnew;

    grid_barrier(p.bar);   // B: states visible for step t+1
  }
}

__global__ void final_kernel(const float* __restrict__ outacc,
                             const float* __restrict__ bo2,
                             float* __restrict__ out, int n) {
  int i = blockIdx.x * 256 + threadIdx.x;
  if (i < n) out[i] = 1.f / (1.f + __expf(-(outacc[i] + bo2[0])));
}

extern "C" void kernel_launch(void* const* d_in, const int* in_sizes, int n_in,
                              void* d_out, int out_size, void* d_ws, size_t ws_size,
                              hipStream_t stream) {
  KParams p;
  p.qs    = (const int*)d_in[0];
  p.cs    = (const int*)d_in[1];
  p.aseq  = (const int*)d_in[2];
  p.pro   = (const float*)d_in[3];
  p.skill = (const float*)d_in[4];
  p.ansv  = (const float*)d_in[5];
  const float* time_embed = (const float*)d_in[6];
  p.lsst  = (const float*)d_in[7];
  p.ps0   = (const float*)d_in[8];
  p.ss0   = (const float*)d_in[9];
  p.adiff = (const float*)d_in[10];
  p.achg  = (const float*)d_in[11];
  p.Wpf = (const float*)d_in[12]; const float* bpf = (const float*)d_in[13];
  p.Wps = (const float*)d_in[14]; p.bps = (const float*)d_in[15];
  p.Wsf = (const float*)d_in[16]; const float* bsf = (const float*)d_in[17];
  p.Wss = (const float*)d_in[18]; p.bss = (const float*)d_in[19];
  p.Waf = (const float*)d_in[20]; const float* baf = (const float*)d_in[21];
  p.Was = (const float*)d_in[22]; p.bas = (const float*)d_in[23];
  p.Wo1 = (const float*)d_in[24]; p.bo1 = (const float*)d_in[25];
  p.Wo2 = (const float*)d_in[26]; const float* bo2 = (const float*)d_in[27];

  char* ws = (char*)d_ws;
  p.TEpf = (float*)(ws + OFF_TEPF);
  p.TEsf = (float*)(ws + OFF_TESF);
  p.CAF  = (float*)(ws + OFF_CAF);
  p.EXla = (__half*)(ws + OFF_EXLA);
  p.EXlp = (__half*)(ws + OFF_EXLP);
  p.EXlc = (__half*)(ws + OFF_EXLC);
  p.EXas = (float*)(ws + OFF_EXAS);
  p.outacc = (float*)(ws + OFF_OACC);
  p.bar  = (unsigned*)(ws + OFF_BAR);
  p.lpi  = (int*)(ws + OFF_LPI);
  p.lci  = (int*)(ws + OFF_LCI);
  p.psh  = (float*)(ws + OFF_PS);
  p.ssh  = (float*)(ws + OFF_SS);
  float* out = (float*)d_out;

  hipMemsetAsync(ws + OFF_BAR, 0, 256, stream);
  hipMemsetAsync(ws + OFF_OACC, 0, (size_t)B_ * S_ * sizeof(float), stream);

  te_kernel<<<200, 256, 0, stream>>>(time_embed, p.Wpf, bpf, p.Wsf, bsf,
                                     (float*)(ws + OFF_TEPF), (float*)(ws + OFF_TESF));
  caf_kernel<<<1, 256, 0, stream>>>(time_embed, p.Waf, baf, (float*)(ws + OFF_CAF));
  lastidx_kernel<<<B_, 256, 0, stream>>>(p.qs, p.cs,
                                         (int*)(ws + OFF_LPI), (int*)(ws + OFF_LCI));

  void* args[] = { &p };
  hipLaunchCooperativeKernel((const void*)scan_coop, dim3(NB), dim3(256),
                             args, 0, stream);

  int n = B_ * S_;
  final_kernel<<<(n + 255) / 256, 256, 0, stream>>>(p.outacc, bo2, out, n);
}

// Round 7
// 10936.387 us; speedup vs baseline: 1.2796x; 1.2796x over previous
//
#include <hip/hip_runtime.h>
#include <hip/hip_fp16.h>
#include <cstdint>
#include <cstddef>

#define B_ 256
#define L_ 200
#define S_ 199
#define D_ 256
#define Q_ 20000
#define C_ 500
#define ROWS 2
#define NBLK 128   // NBLK * ROWS == B_

// ---- workspace layout (bytes, 256-aligned) ----
#define OFF_TEPF 0u            // 204800  f32 [200][256]
#define OFF_TESF 204800u       // 204800
#define OFF_CAF  409600u       // 1024
#define OFF_PPF  410624u       // 131072  f16 uint4 [32][256]
#define OFF_PSF  541696u       // 131072
#define OFF_PAF  672768u       // 131072
#define OFF_PAS  803840u       // 262144  [64][256]
#define OFF_PPS  1065984u      // 262144
#define OFF_PSS  1328128u      // 262144
#define OFF_PO1  1590272u      // 524288  [128][256]
#define OFF_LPI  2114560u      // 203776  int [B][S]
#define OFF_LCI  2318336u      // 203776
#define OFF_PSH  2522112u      // 26083328 f16 [B][S][256]
#define OFF_SSH  28605440u     // 26083328
// total 54,688,768 bytes (~52.2 MB)

// TEpf[tau][d] = bpf[d] + sum_k time_embed[tau][k]*Wpf[d][256+k]; same for sf.
__global__ void te_kernel(const float* __restrict__ te,
                          const float* __restrict__ Wpf, const float* __restrict__ bpf,
                          const float* __restrict__ Wsf, const float* __restrict__ bsf,
                          float* __restrict__ TEpf, float* __restrict__ TEsf) {
  int idx = blockIdx.x * 256 + threadIdx.x;
  int tau = idx >> 8, d = idx & 255;
  const float* ter = te + (tau << 8);
  const float* wp = Wpf + d * 512 + 256;
  const float* ws = Wsf + d * 512 + 256;
  float ap = 0.f, as = 0.f;
  for (int k = 0; k < 256; ++k) {
    float x = ter[k];
    ap = fmaf(x, wp[k], ap);
    as = fmaf(x, ws[k], as);
  }
  TEpf[idx] = ap + bpf[d];
  TEsf[idx] = as + bsf[d];
}

__global__ void caf_kernel(const float* __restrict__ te, const float* __restrict__ Waf,
                           const float* __restrict__ baf, float* __restrict__ CAF) {
  int d = threadIdx.x;
  const float* ter = te + 256;
  const float* wa = Waf + d * 512 + 256;
  float a = 0.f;
  for (int k = 0; k < 256; ++k) a = fmaf(ter[k], wa[k], a);
  CAF[d] = a + baf[d];
}

// lpi[b][t] = largest t'<t with nq[b][t']==nq[b][t], else 0 (matches reference
// lpt-table semantics incl. "never seen" -> 0, since step 0 writes history row 0).
__global__ void lastidx_kernel(const int* __restrict__ q_seq, const int* __restrict__ c_seq,
                               int* __restrict__ lpi, int* __restrict__ lci) {
  int b = blockIdx.x;
  int tid = threadIdx.x;
  __shared__ int sq[S_], sc[S_];
  if (tid < S_) {
    sq[tid] = q_seq[b * L_ + tid + 1];
    sc[tid] = c_seq[b * L_ + tid + 1];
  }
  __syncthreads();
  if (tid < S_) {
    int ip = sq[tid], ic = sc[tid];
    int lp = 0, lc = 0;
    for (int u = tid - 1; u >= 0; --u) if (sq[u] == ip) { lp = u; break; }
    for (int u = tid - 1; u >= 0; --u) if (sc[u] == ic) { lc = u; break; }
    lpi[b * S_ + tid] = lp;
    lci[b * S_ + tid] = lc;
  }
}

__device__ __forceinline__ unsigned pk2(float a, float b) {
  __half2 h = __floats2half2_rn(a, b);
  return *(unsigned*)&h;
}

// Pack W[d][8k8..8k8+7] (fp32, row-major (256,fi)) -> out[k8*256+d] as 8x f16 in uint4.
__global__ void pack_kernel(const float* __restrict__ W, uint4* __restrict__ out, int fi) {
  int k8 = blockIdx.x, d = threadIdx.x;
  const float* r = W + d * fi + (k8 << 3);
  out[k8 * 256 + d] = make_uint4(pk2(r[0], r[1]), pk2(r[2], r[3]),
                                 pk2(r[4], r[5]), pk2(r[6], r[7]));
}

typedef _Float16 h2v __attribute__((ext_vector_type(2)));
union U2H { unsigned u; h2v h; __half2 hh; };

__device__ __forceinline__ float fd2(unsigned w, unsigned x, float acc) {
#if __has_builtin(__builtin_amdgcn_fdot2)
  U2H a; a.u = w; U2H b; b.u = x;
  return __builtin_amdgcn_fdot2(a.h, b.h, acc, false);
#else
  U2H a; a.u = w; U2H b; b.u = x;
  acc = fmaf(__low2float(a.hh),  __low2float(b.hh),  acc);
  acc = fmaf(__high2float(a.hh), __high2float(b.hh), acc);
  return acc;
#endif
}
__device__ __forceinline__ float dot8(uint4 w, uint4 x, float acc) {
  acc = fd2(w.x, x.x, acc); acc = fd2(w.y, x.y, acc);
  acc = fd2(w.z, x.z, acc); acc = fd2(w.w, x.w, acc);
  return acc;
}
__device__ __forceinline__ float sigf(float z) { return 1.f / (1.f + __expf(-z)); }
__device__ __forceinline__ float tanh_fast(float z) { return 1.f - 2.f / (__expf(2.f * z) + 1.f); }

// 128 blocks x 256 threads; block owns ROWS=2 batch rows; thread d = output dim.
// Weights streamed from L2 once per step per block, applied to both rows
// (2x arithmetic intensity vs round 2). No grid sync; ast carried in LDS f32.
__global__ __launch_bounds__(256)
void scan2_kernel(const int* __restrict__ qs, const int* __restrict__ cs,
                  const int* __restrict__ aseq,
                  const float* __restrict__ pro, const float* __restrict__ skill,
                  const float* __restrict__ ansv, const float* __restrict__ lsst,
                  const float* __restrict__ ps0, const float* __restrict__ ss0,
                  const float* __restrict__ adiff, const float* __restrict__ achg,
                  const float* __restrict__ TEpf, const float* __restrict__ TEsf,
                  const float* __restrict__ CAF,
                  const uint4* __restrict__ Ppf, const uint4* __restrict__ Psf,
                  const uint4* __restrict__ Paf,
                  const uint4* __restrict__ Pas, const uint4* __restrict__ Pps,
                  const uint4* __restrict__ Pss, const uint4* __restrict__ Po1,
                  const float* __restrict__ bo1, const float* __restrict__ bas,
                  const float* __restrict__ bps, const float* __restrict__ bss,
                  const float* __restrict__ Wo2, const float* __restrict__ bo2,
                  const int* __restrict__ lpi, const int* __restrict__ lci,
                  __half* __restrict__ psh, __half* __restrict__ ssh,
                  float* __restrict__ out) {
  const int d = threadIdx.x;
  const int b0 = blockIdx.x * ROWS;

  __shared__ __align__(16) __half sLP[ROWS][264], sLC[ROWS][264], sAS[ROWS][264];
  __shared__ __align__(16) __half sLA[ROWS][264], sLP2[ROWS][264], sLC2[ROWS][264];
  __shared__ __align__(16) __half sPE[ROWS][264], sX[ROWS][264];
  __shared__ float s_astf[ROWS][256];
  __shared__ float s_red[4][ROWS];
  __shared__ int s_idx[ROWS][5];   // ip, ic, ia, lpt, lct

  const float caf_d = CAF[d];
  const float bo1_d = bo1[d], bas_d = bas[d], bps_d = bps[d], bss_d = bss[d];
  const float wo2_d = Wo2[d];
  const float bo2v = bo2[0];

  for (int r = 0; r < ROWS; ++r) {
    int row = b0 + r;
    float a = lsst[d];
    s_astf[r][d] = a;
    sAS[r][d] = __float2half(a);
    // lazy history init: only row 0 is ever read before being written
    psh[(size_t)row * S_ * 256 + d] = __float2half(ps0[d]);
    ssh[(size_t)row * S_ * 256 + d] = __float2half(ss0[d]);
  }
  __syncthreads();

#pragma clang loop unroll(disable)
  for (int t = 0; t < S_; ++t) {
    if (d < ROWS) {
      int row = b0 + d;
      s_idx[d][0] = qs[row * L_ + t + 1];
      s_idx[d][1] = cs[row * L_ + t + 1];
      s_idx[d][2] = aseq[row * L_ + t + 1];
      s_idx[d][3] = lpi[row * S_ + t];
      s_idx[d][4] = lci[row * S_ + t];
    }
    __syncthreads();   // S0

    // ---- staging: gathers (NT - keep weights L2-resident) ----
    float lp_v[ROWS], lc_v[ROWS], as_v[ROWS], dtp[ROWS], dtc[ROWS];
#pragma unroll
    for (int r = 0; r < ROWS; ++r) {
      int row = b0 + r;
      int ip = s_idx[r][0], ic = s_idx[r][1], ia = s_idx[r][2];
      int lpt = s_idx[r][3], lct = s_idx[r][4];
      ushort pu = __builtin_nontemporal_load((const ushort*)psh + ((size_t)row * S_ + lpt) * 256 + d);
      ushort su = __builtin_nontemporal_load((const ushort*)ssh + ((size_t)row * S_ + lct) * 256 + d);
      __half ph = *(__half*)&pu, sh = *(__half*)&su;
      lp_v[r] = __half2float(ph); lc_v[r] = __half2float(sh);
      sLP[r][d] = ph; sLC[r][d] = sh;
      as_v[r] = s_astf[r][d];
      dtp[r] = TEpf[(t - lpt) * 256 + d];
      dtc[r] = TEsf[(t - lct) * 256 + d];
      float ad = __builtin_nontemporal_load(adiff + ip);
      float pe = __builtin_nontemporal_load(pro + (size_t)ip * 256 + d)
               + __builtin_nontemporal_load(skill + (size_t)ic * 256 + d)
               + ad * __builtin_nontemporal_load(achg + (size_t)ic * 256 + d);
      sPE[r][d] = __float2half(pe);
      sX[r][d]  = __float2half(pe + ansv[ia * 256 + d]);
    }
    __syncthreads();   // S1

    // ---- phase 1: gate dots (K=256), weight loaded once, used for both rows ----
    float g0[ROWS] = {0.f, 0.f}, g1[ROWS] = {0.f, 0.f}, g2[ROWS] = {0.f, 0.f};
    {
      const uint4* xp0 = (const uint4*)&sLP[0][0];
      const uint4* xp1 = (const uint4*)&sLP[1][0];
      const uint4* xs0 = (const uint4*)&sLC[0][0];
      const uint4* xs1 = (const uint4*)&sLC[1][0];
      const uint4* xa0 = (const uint4*)&sAS[0][0];
      const uint4* xa1 = (const uint4*)&sAS[1][0];
#pragma unroll 4
      for (int k = 0; k < 32; ++k) {
        uint4 w = Ppf[k * 256 + d];
        g0[0] = dot8(w, xp0[k], g0[0]); g0[1] = dot8(w, xp1[k], g0[1]);
        w = Psf[k * 256 + d];
        g1[0] = dot8(w, xs0[k], g1[0]); g1[1] = dot8(w, xs1[k], g1[1]);
        w = Paf[k * 256 + d];
        g2[0] = dot8(w, xa0[k], g2[0]); g2[1] = dot8(w, xa1[k], g2[1]);
      }
    }
    float lp2[ROWS], lc2[ROWS], la2[ROWS];
#pragma unroll
    for (int r = 0; r < ROWS; ++r) {
      lp2[r] = lp_v[r] * sigf(g0[r] + dtp[r]);
      lc2[r] = lc_v[r] * sigf(g1[r] + dtc[r]);
      la2[r] = as_v[r] * sigf(g2[r] + caf_d);
      sLP2[r][d] = __float2half(lp2[r]);
      sLC2[r][d] = __float2half(lc2[r]);
      sLA[r][d]  = __float2half(la2[r]);
    }
    __syncthreads();   // S2

    // ---- phase 2: Wo1 (K=1024: [la|lp2|lc2|pe]) + updates (K=512: [state|x]) ----
    float aO[ROWS] = {0.f, 0.f}, aA[ROWS] = {0.f, 0.f};
    float aP[ROWS] = {0.f, 0.f}, aC[ROWS] = {0.f, 0.f};
    {
      const uint4* la0 = (const uint4*)&sLA[0][0];
      const uint4* la1 = (const uint4*)&sLA[1][0];
      const uint4* p20 = (const uint4*)&sLP2[0][0];
      const uint4* p21 = (const uint4*)&sLP2[1][0];
      const uint4* c20 = (const uint4*)&sLC2[0][0];
      const uint4* c21 = (const uint4*)&sLC2[1][0];
      const uint4* pe0 = (const uint4*)&sPE[0][0];
      const uint4* pe1 = (const uint4*)&sPE[1][0];
      const uint4* x0  = (const uint4*)&sX[0][0];
      const uint4* x1  = (const uint4*)&sX[1][0];
#pragma unroll 4
      for (int k = 0; k < 32; ++k) {
        uint4 w = Po1[k * 256 + d];
        aO[0] = dot8(w, la0[k], aO[0]); aO[1] = dot8(w, la1[k], aO[1]);
        w = Pas[k * 256 + d];
        aA[0] = dot8(w, la0[k], aA[0]); aA[1] = dot8(w, la1[k], aA[1]);
        w = Pps[k * 256 + d];
        aP[0] = dot8(w, p20[k], aP[0]); aP[1] = dot8(w, p21[k], aP[1]);
        w = Pss[k * 256 + d];
        aC[0] = dot8(w, c20[k], aC[0]); aC[1] = dot8(w, c21[k], aC[1]);
      }
#pragma unroll 4
      for (int k = 0; k < 32; ++k) {
        uint4 w = Po1[(32 + k) * 256 + d];
        aO[0] = dot8(w, p20[k], aO[0]); aO[1] = dot8(w, p21[k], aO[1]);
        w = Pas[(32 + k) * 256 + d];
        aA[0] = dot8(w, x0[k], aA[0]); aA[1] = dot8(w, x1[k], aA[1]);
        w = Pps[(32 + k) * 256 + d];
        aP[0] = dot8(w, x0[k], aP[0]); aP[1] = dot8(w, x1[k], aP[1]);
        w = Pss[(32 + k) * 256 + d];
        aC[0] = dot8(w, x0[k], aC[0]); aC[1] = dot8(w, x1[k], aC[1]);
      }
#pragma unroll 4
      for (int k = 0; k < 32; ++k) {
        uint4 w = Po1[(64 + k) * 256 + d];
        aO[0] = dot8(w, c20[k], aO[0]); aO[1] = dot8(w, c21[k], aO[1]);
        w = Po1[(96 + k) * 256 + d];
        aO[0] = dot8(w, pe0[k], aO[0]); aO[1] = dot8(w, pe1[k], aO[1]);
      }
    }

    // ---- output reduce (per row) ----
    const int lane = d & 63, wv = d >> 6;
#pragma unroll
    for (int r = 0; r < ROWS; ++r) {
      float o1 = fmaxf(aO[r] + bo1_d, 0.f) * wo2_d;
      o1 += __shfl_xor(o1, 32); o1 += __shfl_xor(o1, 16);
      o1 += __shfl_xor(o1, 8);  o1 += __shfl_xor(o1, 4);
      o1 += __shfl_xor(o1, 2);  o1 += __shfl_xor(o1, 1);
      if (lane == 0) s_red[wv][r] = o1;
    }

    // ---- state updates ----
#pragma unroll
    for (int r = 0; r < ROWS; ++r) {
      int row = b0 + r;
      float anew = la2[r] + tanh_fast(aA[r] + bas_d);
      float pnew = lp2[r] + tanh_fast(aP[r] + bps_d);
      float cnew = lc2[r] + tanh_fast(aC[r] + bss_d);
      s_astf[r][d] = anew;
      sAS[r][d] = __float2half(anew);      // safe: gate reads ended before S2
      __half ph = __float2half(pnew), ch = __float2half(cnew);
      __builtin_nontemporal_store(*(ushort*)&ph,
          (ushort*)psh + ((size_t)row * S_ + t) * 256 + d);
      __builtin_nontemporal_store(*(ushort*)&ch,
          (ushort*)ssh + ((size_t)row * S_ + t) * 256 + d);
    }
    __syncthreads();   // S3
    if (d < ROWS) {
      float z = s_red[0][d] + s_red[1][d] + s_red[2][d] + s_red[3][d] + bo2v;
      out[(b0 + d) * S_ + t] = 1.f / (1.f + __expf(-z));
    }
  }
}

extern "C" void kernel_launch(void* const* d_in, const int* in_sizes, int n_in,
                              void* d_out, int out_size, void* d_ws, size_t ws_size,
                              hipStream_t stream) {
  const int*   q_seq        = (const int*)d_in[0];
  const int*   c_seq        = (const int*)d_in[1];
  const int*   a_seq        = (const int*)d_in[2];
  const float* pro_embed    = (const float*)d_in[3];
  const float* skill_embed  = (const float*)d_in[4];
  const float* ans_embed    = (const float*)d_in[5];
  const float* time_embed   = (const float*)d_in[6];
  const float* ls_state     = (const float*)d_in[7];
  const float* pro_state0   = (const float*)d_in[8];
  const float* skill_state0 = (const float*)d_in[9];
  const float* akt_diff     = (const float*)d_in[10];
  const float* akt_change   = (const float*)d_in[11];
  const float* Wpf = (const float*)d_in[12]; const float* bpf = (const float*)d_in[13];
  const float* Wps = (const float*)d_in[14]; const float* bps = (const float*)d_in[15];
  const float* Wsf = (const float*)d_in[16]; const float* bsf = (const float*)d_in[17];
  const float* Wss = (const float*)d_in[18]; const float* bss = (const float*)d_in[19];
  const float* Waf = (const float*)d_in[20]; const float* baf = (const float*)d_in[21];
  const float* Was = (const float*)d_in[22]; const float* bas = (const float*)d_in[23];
  const float* Wo1 = (const float*)d_in[24]; const float* bo1 = (const float*)d_in[25];
  const float* Wo2 = (const float*)d_in[26]; const float* bo2 = (const float*)d_in[27];

  char* ws = (char*)d_ws;
  float* TEpf = (float*)(ws + OFF_TEPF);
  float* TEsf = (float*)(ws + OFF_TESF);
  float* CAF  = (float*)(ws + OFF_CAF);
  uint4* Ppf  = (uint4*)(ws + OFF_PPF);
  uint4* Psf  = (uint4*)(ws + OFF_PSF);
  uint4* Paf  = (uint4*)(ws + OFF_PAF);
  uint4* Pas  = (uint4*)(ws + OFF_PAS);
  uint4* Pps  = (uint4*)(ws + OFF_PPS);
  uint4* Pss  = (uint4*)(ws + OFF_PSS);
  uint4* Po1  = (uint4*)(ws + OFF_PO1);
  int*   lpi  = (int*)(ws + OFF_LPI);
  int*   lci  = (int*)(ws + OFF_LCI);
  __half* psh = (__half*)(ws + OFF_PSH);
  __half* ssh = (__half*)(ws + OFF_SSH);
  float* out  = (float*)d_out;

  te_kernel<<<200, 256, 0, stream>>>(time_embed, Wpf, bpf, Wsf, bsf, TEpf, TEsf);
  caf_kernel<<<1, 256, 0, stream>>>(time_embed, Waf, baf, CAF);
  lastidx_kernel<<<B_, 256, 0, stream>>>(q_seq, c_seq, lpi, lci);

  // gate matrices: left halves (K=256) -> 32 k8-blocks
  pack_kernel<<<32, 256, 0, stream>>>(Wpf, Ppf, 512);
  pack_kernel<<<32, 256, 0, stream>>>(Wsf, Psf, 512);
  pack_kernel<<<32, 256, 0, stream>>>(Waf, Paf, 512);
  // full K=512 update matrices
  pack_kernel<<<64, 256, 0, stream>>>(Was, Pas, 512);
  pack_kernel<<<64, 256, 0, stream>>>(Wps, Pps, 512);
  pack_kernel<<<64, 256, 0, stream>>>(Wss, Pss, 512);
  // Wo1: K=1024
  pack_kernel<<<128, 256, 0, stream>>>(Wo1, Po1, 1024);

  scan2_kernel<<<NBLK, 256, 0, stream>>>(q_seq, c_seq, a_seq,
                                         pro_embed, skill_embed, ans_embed,
                                         ls_state, pro_state0, skill_state0,
                                         akt_diff, akt_change,
                                         TEpf, TEsf, CAF,
                                         Ppf, Psf, Paf, Pas, Pps, Pss, Po1,
                                         bo1, bas, bps, bss, Wo2, bo2,
                                         lpi, lci, psh, ssh, out);
}